// Round 9
// baseline (494.730 us; speedup 1.0000x reference)
//
#include <hip/hip_runtime.h>
#include <math.h>

#define G     128
#define NPER  512
#define NTOT  65536
#define E_TOT 1048576
#define EPG   8192
#define INC   100
#define HID   128
#define KP1   410
#define KP2   328
#define KP3   263

// ---------------------------------------------------------------------------
// init: identity cmap (short), zero sread + 3 per-layer bnpart buffers
// ---------------------------------------------------------------------------
__global__ void init_kernel(short* __restrict__ cmap, float* __restrict__ sread,
                            float* __restrict__ bnpart) {
    int t = blockIdx.x * 256 + threadIdx.x;
    if (t < NTOT) cmap[t] = (short)(t & (NPER - 1));
    if (t < G * 256) sread[t] = 0.f;
    if (t < 3 * G * 256) bnpart[t] = 0.f;
}

// ---------------------------------------------------------------------------
// csr_build0: layer-1 CSR (identity mapping, all edges valid).
// ---------------------------------------------------------------------------
__global__ __launch_bounds__(512, 2) void csr_build0(
    const int* __restrict__ src, const int* __restrict__ dst,
    unsigned short* __restrict__ csr_g, int* __restrict__ rowptr_g)
{
    __shared__ int cnt_s[NPER];
    __shared__ int rowptr_s[NPER + 1];
    __shared__ int wo_s[NPER];
    __shared__ int chunksum_s[9];

    const int g = blockIdx.x, tid = threadIdx.x, lane = tid & 63, wv = tid >> 6;
    const int ebase = g * EPG, obase = g * NPER;

    cnt_s[tid] = 0;
    __syncthreads();
    for (int e = tid; e < EPG; e += 512)
        atomicAdd(&cnt_s[dst[ebase + e] - obase], 1);
    __syncthreads();

    int v = cnt_s[tid], x = v;
#pragma unroll
    for (int d = 1; d < 64; d <<= 1) {
        int y = __shfl_up(x, d);
        if (lane >= d) x += y;
    }
    if (lane == 63) chunksum_s[wv] = x;
    __syncthreads();
    if (tid == 0) {
        int acc = 0;
#pragma unroll
        for (int k = 0; k < 8; ++k) { int t = chunksum_s[k]; chunksum_s[k] = acc; acc += t; }
    }
    __syncthreads();
    int excl = x - v + chunksum_s[wv];
    rowptr_s[tid] = excl; wo_s[tid] = excl;
    if (tid == 511) rowptr_s[512] = excl + v;
    __syncthreads();

    for (int i = tid; i <= NPER; i += 512) rowptr_g[g * 513 + i] = rowptr_s[i];
    for (int e = tid; e < EPG; e += 512) {
        int sl = src[ebase + e] - obase, dl = dst[ebase + e] - obase;
        int pos = atomicAdd(&wo_s[dl], 1);
        csr_g[g * EPG + pos] = (unsigned short)sl;
    }
}

// ---------------------------------------------------------------------------
// gemm_pre: out = relu(A[M x 100] @ W[100 x 128] + b). Single-buffer KC=32.
// ---------------------------------------------------------------------------
__global__ __launch_bounds__(256, 2) void gemm_pre(
    const float* __restrict__ A, const float* __restrict__ W,
    const float* __restrict__ bias, float* __restrict__ out, int M)
{
    constexpr int K = INC, KC = 32;
    __shared__ float Ws[KC][128];
    __shared__ float As[KC][132];
    const int tid  = threadIdx.x;
    const int row0 = blockIdx.x * 128;
    const int r0 = (tid >> 4) * 8;
    const int c0 = (tid & 15) * 8;

    float acc[8][8];
#pragma unroll
    for (int i = 0; i < 8; ++i)
#pragma unroll
        for (int j = 0; j < 8; ++j) acc[i][j] = 0.f;

    for (int k0 = 0; k0 < K; k0 += KC) {
        const int kc  = (K - k0 < KC) ? (K - k0) : KC;
        const int nf4 = kc >> 2;

        for (int i = tid; i < kc * 32; i += 256) {
            int kk = i >> 5, c4 = i & 31;
            *((float4*)&Ws[kk][0] + c4) =
                *((const float4*)(W + (size_t)(k0 + kk) * 128) + c4);
        }
        for (int i = tid; i < nf4 * 128; i += 256) {
            int row = i / nf4, f4 = i - row * nf4;
            float4 v = *(const float4*)(A + (size_t)(row0 + row) * K + k0 + f4 * 4);
            As[f4 * 4 + 0][row] = v.x;
            As[f4 * 4 + 1][row] = v.y;
            As[f4 * 4 + 2][row] = v.z;
            As[f4 * 4 + 3][row] = v.w;
        }
        __syncthreads();

#pragma unroll 4
        for (int kk = 0; kk < kc; ++kk) {
            float4 b0 = *(const float4*)&Ws[kk][c0];
            float4 b1 = *(const float4*)&Ws[kk][c0 + 4];
            float4 a0 = *(const float4*)&As[kk][r0];
            float4 a1 = *(const float4*)&As[kk][r0 + 4];
            float a[8] = {a0.x, a0.y, a0.z, a0.w, a1.x, a1.y, a1.z, a1.w};
            float b[8] = {b0.x, b0.y, b0.z, b0.w, b1.x, b1.y, b1.z, b1.w};
#pragma unroll
            for (int i = 0; i < 8; ++i)
#pragma unroll
                for (int j = 0; j < 8; ++j)
                    acc[i][j] += a[i] * b[j];
        }
        __syncthreads();
    }

#pragma unroll
    for (int i = 0; i < 8; ++i) {
        int row = row0 + r0 + i;
        float o[8];
#pragma unroll
        for (int j = 0; j < 8; ++j)
            o[j] = fmaxf(acc[i][j] + bias[c0 + j], 0.f);
        float* po = out + (size_t)row * 128 + c0;
        *(float4*)po       = make_float4(o[0], o[1], o[2], o[3]);
        *(float4*)(po + 4) = make_float4(o[4], o[5], o[6], o[7]);
    }
}

// ---------------------------------------------------------------------------
// gemm128<NCUR>: out[row] = dinv_row * (A[row] @ W), K=128, double-buffered
// LDS (reg-staged prefetch, one sync per chunk). dinv from rowptr diffs.
// ---------------------------------------------------------------------------
template<int NCUR>
__global__ __launch_bounds__(256, 2) void gemm128(
    const float* __restrict__ A, const float* __restrict__ W,
    const int* __restrict__ rowptr_g, float* __restrict__ out)
{
    constexpr int KC = 32;
    __shared__ float Ws[2][KC][128];
    __shared__ float As[2][KC][132];
    __shared__ float dinv_ls[128];
    const int tid  = threadIdx.x;
    const int row0 = blockIdx.x * 128;
    const int r0 = (tid >> 4) * 8;
    const int c0 = (tid & 15) * 8;

    if (tid < 128) {
        int row = row0 + tid;
        int gg = row / NCUR, ll = row - gg * NCUR;
        const int* rp = rowptr_g + gg * 513 + ll;
        dinv_ls[tid] = rsqrtf((float)(rp[1] - rp[0] + 1));
    }

    const float4* W4 = (const float4*)W;

    // stage chunk 0 -> buffer 0
#pragma unroll
    for (int j = 0; j < 4; ++j) {
        int i = tid + j * 256;
        int kk = i >> 5, c4 = i & 31;
        *((float4*)&Ws[0][kk][0] + c4) = W4[kk * 32 + c4];
    }
#pragma unroll
    for (int j = 0; j < 4; ++j) {
        int i = tid + j * 256;
        int row = i >> 3, f4 = i & 7;
        float4 v = *(const float4*)(A + (size_t)(row0 + row) * 128 + f4 * 4);
        As[0][f4 * 4 + 0][row] = v.x;
        As[0][f4 * 4 + 1][row] = v.y;
        As[0][f4 * 4 + 2][row] = v.z;
        As[0][f4 * 4 + 3][row] = v.w;
    }
    __syncthreads();

    float acc[8][8];
#pragma unroll
    for (int i = 0; i < 8; ++i)
#pragma unroll
        for (int j = 0; j < 8; ++j) acc[i][j] = 0.f;

    int p = 0;
    for (int k0 = 0; k0 < 128; k0 += KC) {
        const int kn = k0 + KC;
        const bool has = kn < 128;

        float4 wreg[4], areg[4];
        if (has) {
#pragma unroll
            for (int j = 0; j < 4; ++j) {
                int i = tid + j * 256;
                int kk = i >> 5, c4 = i & 31;
                wreg[j] = W4[(kn + kk) * 32 + c4];
            }
#pragma unroll
            for (int j = 0; j < 4; ++j) {
                int i = tid + j * 256;
                int row = i >> 3, f4 = i & 7;
                areg[j] = *(const float4*)(A + (size_t)(row0 + row) * 128 + kn + f4 * 4);
            }
        }

#pragma unroll 4
        for (int kk = 0; kk < KC; ++kk) {
            float4 b0 = *(const float4*)&Ws[p][kk][c0];
            float4 b1 = *(const float4*)&Ws[p][kk][c0 + 4];
            float4 a0 = *(const float4*)&As[p][kk][r0];
            float4 a1 = *(const float4*)&As[p][kk][r0 + 4];
            float a[8] = {a0.x, a0.y, a0.z, a0.w, a1.x, a1.y, a1.z, a1.w};
            float b[8] = {b0.x, b0.y, b0.z, b0.w, b1.x, b1.y, b1.z, b1.w};
#pragma unroll
            for (int i = 0; i < 8; ++i)
#pragma unroll
                for (int j = 0; j < 8; ++j)
                    acc[i][j] += a[i] * b[j];
        }

        if (has) {
            int q = p ^ 1;
#pragma unroll
            for (int j = 0; j < 4; ++j) {
                int i = tid + j * 256;
                int kk = i >> 5, c4 = i & 31;
                *((float4*)&Ws[q][kk][0] + c4) = wreg[j];
            }
#pragma unroll
            for (int j = 0; j < 4; ++j) {
                int i = tid + j * 256;
                int row = i >> 3, f4 = i & 7;
                float4 v = areg[j];
                As[q][f4 * 4 + 0][row] = v.x;
                As[q][f4 * 4 + 1][row] = v.y;
                As[q][f4 * 4 + 2][row] = v.z;
                As[q][f4 * 4 + 3][row] = v.w;
            }
        }
        __syncthreads();
        p ^= 1;
    }

#pragma unroll
    for (int i = 0; i < 8; ++i) {
        int row = row0 + r0 + i;
        float dv = dinv_ls[r0 + i];
        float o[8];
#pragma unroll
        for (int j = 0; j < 8; ++j) o[j] = acc[i][j] * dv;
        float* po = out + (size_t)row * 128 + c0;
        *(float4*)po       = make_float4(o[0], o[1], o[2], o[3]);
        *(float4*)(po + 4) = make_float4(o[4], o[5], o[6], o[7]);
    }
}

// ---------------------------------------------------------------------------
// gather v5: input xs is PRE-SCALED (row r already times dinv_r).
//   grid (G,16), 256 threads, 8 blocks/CU. Inner loop per edge:
//   csr LDS read + 512B global load + float2 add. Dual-row ILP.
// ---------------------------------------------------------------------------
template<int NCUR>
__global__ __launch_bounds__(256, 8) void gather_kernel(
    const float* __restrict__ xs, const unsigned short* __restrict__ csr_g,
    const int* __restrict__ rowptr_g, const float* __restrict__ bvec,
    float* __restrict__ out, float* __restrict__ bnpart)
{
    constexpr int CHUNK = (NCUR + 15) / 16;
    constexpr int CSRCAP = 1536;
    __shared__ int   rowptr_s[CHUNK + 1];
    __shared__ unsigned short csr_s[CSRCAP];
    __shared__ float red_s[512];

    const int g = blockIdx.x, s = blockIdx.y;
    const int tid = threadIdx.x, lane = tid & 63, w = tid >> 6;
    const int nbase = g * NCUR;
    const int d0 = s * CHUNK;
    const int d1 = (d0 + CHUNK < NCUR) ? d0 + CHUNK : NCUR;
    const int len = d1 - d0;

    const int* rp = rowptr_g + g * 513 + d0;
    for (int i = tid; i <= len; i += 256) rowptr_s[i] = rp[i];
    __syncthreads();

    const int base = rowptr_s[0];
    int nume = rowptr_s[len] - base;
    if (nume > CSRCAP) nume = CSRCAP;
    const unsigned short* cg = csr_g + g * EPG + base;
    for (int i = tid; i < nume; i += 256) csr_s[i] = cg[i];
    __syncthreads();

    const float2* x2g = (const float2*)xs + (size_t)nbase * 64 + lane;
    float2* o2p = (float2*)out;
    const float2 b2 = ((const float2*)bvec)[lane];
    float2 sum = make_float2(0.f, 0.f), sq = make_float2(0.f, 0.f);

    for (int da = d0 + w; da < d1; da += 8) {
        const int db = da + 4;
        const bool hb = db < d1;
        const int ra = da - d0, rb = db - d0;
        const int ia = rowptr_s[ra] - base;
        const int na = rowptr_s[ra + 1] - rowptr_s[ra];
        const int ib = hb ? rowptr_s[rb] - base : 0;
        const int nbl = hb ? rowptr_s[rb + 1] - rowptr_s[rb] : 0;
        const float dva = rsqrtf((float)(na + 1));
        const float dvb = rsqrtf((float)(nbl + 1));

        float2 accA = x2g[(size_t)da * 64];         // self term (pre-scaled)
        float2 accB = make_float2(0.f, 0.f);
        if (hb) accB = x2g[(size_t)db * 64];

        const int nmin = na < nbl ? na : nbl;
#pragma unroll 2
        for (int t = 0; t < nmin; ++t) {
            int sa = csr_s[ia + t], sb = csr_s[ib + t];
            float2 va = x2g[(size_t)sa * 64];
            float2 vb = x2g[(size_t)sb * 64];
            accA.x += va.x; accA.y += va.y;
            accB.x += vb.x; accB.y += vb.y;
        }
#pragma unroll 4
        for (int t = nmin; t < na; ++t) {
            float2 va = x2g[(size_t)csr_s[ia + t] * 64];
            accA.x += va.x; accA.y += va.y;
        }
#pragma unroll 4
        for (int t = nmin; t < nbl; ++t) {
            float2 vb = x2g[(size_t)csr_s[ib + t] * 64];
            accB.x += vb.x; accB.y += vb.y;
        }

        float2 oA = make_float2(b2.x + dva * accA.x, b2.y + dva * accA.y);
        o2p[(size_t)(nbase + da) * 64 + lane] = oA;
        sum.x += oA.x; sum.y += oA.y;
        sq.x  += oA.x * oA.x; sq.y += oA.y * oA.y;
        if (hb) {
            float2 oB = make_float2(b2.x + dvb * accB.x, b2.y + dvb * accB.y);
            o2p[(size_t)(nbase + db) * 64 + lane] = oB;
            sum.x += oB.x; sum.y += oB.y;
            sq.x  += oB.x * oB.x; sq.y += oB.y * oB.y;
        }
    }

    float2* red2 = (float2*)red_s;
    red2[tid] = sum; __syncthreads();
    if (tid < 64) {
        float2 a = red2[tid], b_ = red2[tid + 64],
               c = red2[tid + 128], d_ = red2[tid + 192];
        atomicAdd(&bnpart[g * 256 + 2 * tid],     a.x + b_.x + c.x + d_.x);
        atomicAdd(&bnpart[g * 256 + 2 * tid + 1], a.y + b_.y + c.y + d_.y);
    }
    __syncthreads();
    red2[tid] = sq; __syncthreads();
    if (tid < 64) {
        float2 a = red2[tid], b_ = red2[tid + 64],
               c = red2[tid + 128], d_ = red2[tid + 192];
        atomicAdd(&bnpart[g * 256 + 128 + 2 * tid],     a.x + b_.x + c.x + d_.x);
        atomicAdd(&bnpart[g * 256 + 128 + 2 * tid + 1], a.y + b_.y + c.y + d_.y);
    }
}

// ---------------------------------------------------------------------------
// pool: 1024 threads per graph. phase 0 computes BN coefs + att norm in LDS
// (redundant per block, from per-layer bnpart). Then scores -> rank-select ->
// gate/readout -> cmap remap; if BUILD: next layer's CSR+rowptr.
// ---------------------------------------------------------------------------
template<int NCUR, int KK, bool BUILD>
__global__ __launch_bounds__(1024, 1) void pool_kernel(
    const float* __restrict__ gcn, float* __restrict__ newx,
    short* __restrict__ cmap, float* __restrict__ sread,
    const float* __restrict__ bnpart, float n,
    const float* __restrict__ gamma, const float* __restrict__ beta,
    const float* __restrict__ att,
    const int* __restrict__ src, const int* __restrict__ dst,
    unsigned short* __restrict__ csr_g, int* __restrict__ rowptr_g)
{
    __shared__ float coef_s[384];
    __shared__ float Stmp[128], Qtmp[128], attr[128];
    __shared__ float score_s[NCUR];
    __shared__ unsigned long long key_s[NCUR];
    __shared__ short o2n_s[NCUR];
    __shared__ unsigned short n2o_s[KK];
    __shared__ short cmap_s[NPER];
    __shared__ float2 red2[1024];
    __shared__ int   cnt_s[512];
    __shared__ int   rowptr_s[513];
    __shared__ int   wo_s[512];
    __shared__ int   chunksum_s[9];

    const int g = blockIdx.x, tid = threadIdx.x, lane = tid & 63, w = tid >> 6;
    const int nb = g * NCUR;
    const int ebase = g * EPG, obase = g * NPER;

    // phase 0a: reduce bnpart over graphs; att^2
    if (tid < 128) {
        float S = 0.f;
#pragma unroll 4
        for (int g2 = 0; g2 < G; ++g2) S += bnpart[g2 * 256 + tid];
        Stmp[tid] = S;
        float av = att[tid]; attr[tid] = av * av;
    } else if (tid < 256) {
        int t = tid - 128;
        float Q = 0.f;
#pragma unroll 4
        for (int g2 = 0; g2 < G; ++g2) Q += bnpart[g2 * 256 + 128 + t];
        Qtmp[t] = Q;
    }
    for (int i = tid; i < NPER; i += 1024) cmap_s[i] = cmap[obase + i];
    __syncthreads();
    for (int st = 64; st > 0; st >>= 1) {
        if (tid < st) attr[tid] += attr[tid + st];
        __syncthreads();
    }
    if (tid < 128) {
        float norm = sqrtf(attr[0]);
        float mu   = Stmp[tid] / n;
        float var  = Qtmp[tid] / n - mu * mu;
        float a    = gamma[tid] * rsqrtf(var + 1e-5f);
        coef_s[tid]       = a;
        coef_s[128 + tid] = beta[tid] - mu * a;
        coef_s[256 + tid] = att[tid] / norm;
    }
    __syncthreads();

    const float a0 = coef_s[lane],       a1 = coef_s[64 + lane];
    const float c0 = coef_s[128 + lane], c1 = coef_s[192 + lane];
    const float t0 = coef_s[256 + lane], t1 = coef_s[320 + lane];

    // A: scores, one wave per node
    for (int i = w; i < NCUR; i += 16) {
        const float* row = gcn + (size_t)(nb + i) * 128;
        float h0 = fmaxf(a0 * row[lane] + c0, 0.f);
        float h1 = fmaxf(a1 * row[64 + lane] + c1, 0.f);
        float p  = h0 * t0 + h1 * t1;
#pragma unroll
        for (int off = 32; off > 0; off >>= 1) p += __shfl_down(p, off);
        if (lane == 0) score_s[i] = tanhf(p);
    }
    __syncthreads();

    // B: composite keys
    for (int i = tid; i < NCUR; i += 1024) {
        unsigned u   = __float_as_uint(score_s[i]);
        unsigned key = (u & 0x80000000u) ? ~u : (u | 0x80000000u);
        key_s[i] = ((unsigned long long)key << 32) |
                   (unsigned long long)(0xFFFFFFFFu - (unsigned)i);
    }
    __syncthreads();

    // C: rank selection
    for (int i = tid; i < NCUR; i += 1024) {
        const unsigned long long ki = key_s[i];
        int r = 0;
#pragma unroll 8
        for (int j = 0; j < NCUR; ++j) r += (key_s[j] > ki) ? 1 : 0;
        o2n_s[i] = (r < KK) ? (short)r : (short)-1;
        if (r < KK) n2o_s[r] = (unsigned short)i;
    }
    __syncthreads();

    // D: gating + newx + readout partials
    float mx0 = -1e30f, mx1 = -1e30f, sm0 = 0.f, sm1 = 0.f;
    for (int j2 = w; j2 < KK; j2 += 16) {
        int old = n2o_s[j2];
        float s = score_s[old];
        const float* row = gcn + (size_t)(nb + old) * 128;
        float h0 = fmaxf(a0 * row[lane] + c0, 0.f) * s;
        float h1 = fmaxf(a1 * row[64 + lane] + c1, 0.f) * s;
        float* orow = newx + (size_t)(g * KK + j2) * 128;
        orow[lane]      = h0;
        orow[64 + lane] = h1;
        mx0 = fmaxf(mx0, h0); mx1 = fmaxf(mx1, h1);
        sm0 += h0; sm1 += h1;
    }
    red2[tid] = make_float2(mx0, mx1);
    __syncthreads();
    if (tid < 64) {
        float m = -1e30f;
#pragma unroll
        for (int w2 = 0; w2 < 16; ++w2) m = fmaxf(m, red2[w2 * 64 + tid].x);
        sread[g * 256 + tid] += m;
    } else if (tid < 128) {
        int l = tid - 64;
        float m = -1e30f;
#pragma unroll
        for (int w2 = 0; w2 < 16; ++w2) m = fmaxf(m, red2[w2 * 64 + l].y);
        sread[g * 256 + tid] += m;
    }
    __syncthreads();
    red2[tid] = make_float2(sm0, sm1);
    __syncthreads();
    if (tid < 64) {
        float sm = 0.f;
#pragma unroll
        for (int w2 = 0; w2 < 16; ++w2) sm += red2[w2 * 64 + tid].x;
        sread[g * 256 + 128 + tid] += sm * (1.0f / KK);
    } else if (tid < 128) {
        int l = tid - 64;
        float sm = 0.f;
#pragma unroll
        for (int w2 = 0; w2 < 16; ++w2) sm += red2[w2 * 64 + l].y;
        sread[g * 256 + 128 + tid] += sm * (1.0f / KK);
    }

    // E: cmap remap
    for (int o = tid; o < NPER; o += 1024) {
        int m = cmap_s[o];
        short nm = (m >= 0) ? o2n_s[m] : (short)-1;
        cmap_s[o] = nm;
        cmap[obase + o] = nm;
    }

    if (!BUILD) return;
    __syncthreads();

    // F: build next layer's CSR
    if (tid < 512) cnt_s[tid] = 0;
    __syncthreads();
    for (int e = tid; e < EPG; e += 1024) {
        int sl = cmap_s[src[ebase + e] - obase];
        int dl = cmap_s[dst[ebase + e] - obase];
        if ((sl | dl) >= 0) atomicAdd(&cnt_s[dl], 1);
    }
    __syncthreads();
    int v = 0, x = 0;
    if (tid < 512) {
        v = cnt_s[tid]; x = v;
#pragma unroll
        for (int d = 1; d < 64; d <<= 1) {
            int y = __shfl_up(x, d);
            if (lane >= d) x += y;
        }
        if (lane == 63) chunksum_s[w] = x;
    }
    __syncthreads();
    if (tid == 0) {
        int acc = 0;
#pragma unroll
        for (int k = 0; k < 8; ++k) { int t = chunksum_s[k]; chunksum_s[k] = acc; acc += t; }
    }
    __syncthreads();
    if (tid < 512) {
        int excl = x - v + chunksum_s[w];
        rowptr_s[tid] = excl; wo_s[tid] = excl;
        if (tid == 511) rowptr_s[512] = excl + v;
    }
    __syncthreads();
    for (int i = tid; i <= 512; i += 1024) rowptr_g[g * 513 + i] = rowptr_s[i];
    for (int e = tid; e < EPG; e += 1024) {
        int sl = cmap_s[src[ebase + e] - obase];
        int dl = cmap_s[dst[ebase + e] - obase];
        if ((sl | dl) >= 0) {
            int pos = atomicAdd(&wo_s[dl], 1);
            csr_g[g * EPG + pos] = (unsigned short)sl;
        }
    }
}

// ---------------------------------------------------------------------------
// final MLP
// ---------------------------------------------------------------------------
__global__ void final_kernel(const float* __restrict__ sread,
                             const float* __restrict__ Wl1,
                             const float* __restrict__ bl1,
                             const float* __restrict__ Wl2,
                             const float* __restrict__ bl2,
                             float* __restrict__ out)
{
    __shared__ float s_s[256];
    __shared__ float hid_s[128];
    int g = blockIdx.x, t = threadIdx.x;
    s_s[t]       = sread[g * 256 + t];
    s_s[128 + t] = sread[g * 256 + 128 + t];
    __syncthreads();
    float acc = bl1[t];
    for (int i = 0; i < 256; ++i) acc += s_s[i] * Wl1[i * 128 + t];
    hid_s[t] = fmaxf(acc, 0.f);
    __syncthreads();
    if (t < 2) {
        float o = bl2[t];
        for (int j = 0; j < 128; ++j) o += hid_s[j] * Wl2[j * 2 + t];
        out[g * 2 + t] = o;
    }
}

// ---------------------------------------------------------------------------
extern "C" void kernel_launch(void* const* d_in, const int* in_sizes, int n_in,
                              void* d_out, int out_size, void* d_ws, size_t ws_size,
                              hipStream_t stream)
{
    const float* x    = (const float*)d_in[0];
    const int*   ei   = (const int*)d_in[1];
    const float* Wp   = (const float*)d_in[3];
    const float* bp   = (const float*)d_in[4];
    const float* W1   = (const float*)d_in[5];
    const float* b1   = (const float*)d_in[6];
    const float* g1   = (const float*)d_in[7];
    const float* be1  = (const float*)d_in[8];
    const float* att1 = (const float*)d_in[9];
    const float* W2   = (const float*)d_in[10];
    const float* b2   = (const float*)d_in[11];
    const float* g2   = (const float*)d_in[12];
    const float* be2  = (const float*)d_in[13];
    const float* att2 = (const float*)d_in[14];
    const float* W3   = (const float*)d_in[15];
    const float* b3   = (const float*)d_in[16];
    const float* g3   = (const float*)d_in[17];
    const float* be3  = (const float*)d_in[18];
    const float* att3 = (const float*)d_in[19];
    const float* Wl1  = (const float*)d_in[20];
    const float* bl1  = (const float*)d_in[21];
    const float* Wl2  = (const float*)d_in[22];
    const float* bl2  = (const float*)d_in[23];
    float* out = (float*)d_out;

    const int* srcp = ei;
    const int* dstp = ei + E_TOT;

    char* ws = (char*)d_ws;
    float*          bufA   = (float*)ws;                      // 33,554,432 B
    float*          bufB   = (float*)(ws + 33554432);         // 33,554,432 B
    unsigned short* csr    = (unsigned short*)(ws + 67108864);//  2,097,152 B
    int*            rowptr = (int*)  (ws + 69206016);         //    262,656 B
    float*          bnpart = (float*)(ws + 69468672);         //    393,216 B (3 layers)
    short*          cmap   = (short*)(ws + 69861888);         //    131,072 B
    float*          sread  = (float*)(ws + 69992960);         //    131,072 B

    float* bn0 = bnpart;
    float* bn1 = bnpart + G * 256;
    float* bn2 = bnpart + 2 * G * 256;

    init_kernel<<<384, 256, 0, stream>>>(cmap, sread, bnpart);
    csr_build0<<<G, 512, 0, stream>>>(srcp, dstp, csr, rowptr);

    // h0 = relu(x @ Wp + bp)
    gemm_pre<<<512, 256, 0, stream>>>(x, Wp, bp, bufA, NTOT);

    // ---- layer 1 ----
    gemm128<NPER><<<512, 256, 0, stream>>>(bufA, W1, rowptr, bufB);
    gather_kernel<NPER><<<dim3(G, 16), 256, 0, stream>>>(bufB, csr, rowptr, b1, bufA, bn0);
    pool_kernel<NPER, KP1, true><<<G, 1024, 0, stream>>>(
        bufA, bufB, cmap, sread, bn0, (float)NTOT, g1, be1, att1,
        srcp, dstp, csr, rowptr);

    // ---- layer 2 ----
    gemm128<KP1><<<410, 256, 0, stream>>>(bufB, W2, rowptr, bufA);
    gather_kernel<KP1><<<dim3(G, 16), 256, 0, stream>>>(bufA, csr, rowptr, b2, bufB, bn1);
    pool_kernel<KP1, KP2, true><<<G, 1024, 0, stream>>>(
        bufB, bufA, cmap, sread, bn1, (float)(G * KP1), g2, be2, att2,
        srcp, dstp, csr, rowptr);

    // ---- layer 3 ----
    gemm128<KP2><<<328, 256, 0, stream>>>(bufA, W3, rowptr, bufB);
    gather_kernel<KP2><<<dim3(G, 16), 256, 0, stream>>>(bufB, csr, rowptr, b3, bufA, bn2);
    pool_kernel<KP2, KP3, false><<<G, 1024, 0, stream>>>(
        bufA, bufB, cmap, sread, bn2, (float)(G * KP2), g3, be3, att3,
        srcp, dstp, csr, rowptr);

    final_kernel<<<G, 128, 0, stream>>>(sread, Wl1, bl1, Wl2, bl2, out);
}

// Round 10
// 485.572 us; speedup vs baseline: 1.0189x; 1.0189x over previous
//
#include <hip/hip_runtime.h>
#include <math.h>

#define G     128
#define NPER  512
#define NTOT  65536
#define E_TOT 1048576
#define EPG   8192
#define INC   100
#define HID   128
#define KP1   410
#define KP2   328
#define KP3   263

// ---------------------------------------------------------------------------
// init: identity cmap (short), zero sread + 3 per-layer bnpart buffers
// ---------------------------------------------------------------------------
__global__ void init_kernel(short* __restrict__ cmap, float* __restrict__ sread,
                            float* __restrict__ bnpart) {
    int t = blockIdx.x * 256 + threadIdx.x;
    if (t < NTOT) cmap[t] = (short)(t & (NPER - 1));
    if (t < G * 256) sread[t] = 0.f;
    if (t < 3 * G * 256) bnpart[t] = 0.f;
}

// ---------------------------------------------------------------------------
// csr_build0: layer-1 CSR (identity mapping, all edges valid).
// ---------------------------------------------------------------------------
__global__ __launch_bounds__(512, 2) void csr_build0(
    const int* __restrict__ src, const int* __restrict__ dst,
    unsigned short* __restrict__ csr_g, int* __restrict__ rowptr_g)
{
    __shared__ int cnt_s[NPER];
    __shared__ int rowptr_s[NPER + 1];
    __shared__ int wo_s[NPER];
    __shared__ int chunksum_s[9];

    const int g = blockIdx.x, tid = threadIdx.x, lane = tid & 63, wv = tid >> 6;
    const int ebase = g * EPG, obase = g * NPER;

    cnt_s[tid] = 0;
    __syncthreads();
    for (int e = tid; e < EPG; e += 512)
        atomicAdd(&cnt_s[dst[ebase + e] - obase], 1);
    __syncthreads();

    int v = cnt_s[tid], x = v;
#pragma unroll
    for (int d = 1; d < 64; d <<= 1) {
        int y = __shfl_up(x, d);
        if (lane >= d) x += y;
    }
    if (lane == 63) chunksum_s[wv] = x;
    __syncthreads();
    if (tid == 0) {
        int acc = 0;
#pragma unroll
        for (int k = 0; k < 8; ++k) { int t = chunksum_s[k]; chunksum_s[k] = acc; acc += t; }
    }
    __syncthreads();
    int excl = x - v + chunksum_s[wv];
    rowptr_s[tid] = excl; wo_s[tid] = excl;
    if (tid == 511) rowptr_s[512] = excl + v;
    __syncthreads();

    for (int i = tid; i <= NPER; i += 512) rowptr_g[g * 513 + i] = rowptr_s[i];
    for (int e = tid; e < EPG; e += 512) {
        int sl = src[ebase + e] - obase, dl = dst[ebase + e] - obase;
        int pos = atomicAdd(&wo_s[dl], 1);
        csr_g[g * EPG + pos] = (unsigned short)sl;
    }
}

// ---------------------------------------------------------------------------
// gemm_pre: out = relu(A[M x 100] @ W[100 x 128] + b). Single-buffer KC=32.
// ---------------------------------------------------------------------------
__global__ __launch_bounds__(256, 2) void gemm_pre(
    const float* __restrict__ A, const float* __restrict__ W,
    const float* __restrict__ bias, float* __restrict__ out, int M)
{
    constexpr int K = INC, KC = 32;
    __shared__ float Ws[KC][128];
    __shared__ float As[KC][132];
    const int tid  = threadIdx.x;
    const int row0 = blockIdx.x * 128;
    const int r0 = (tid >> 4) * 8;
    const int c0 = (tid & 15) * 8;

    float acc[8][8];
#pragma unroll
    for (int i = 0; i < 8; ++i)
#pragma unroll
        for (int j = 0; j < 8; ++j) acc[i][j] = 0.f;

    for (int k0 = 0; k0 < K; k0 += KC) {
        const int kc  = (K - k0 < KC) ? (K - k0) : KC;
        const int nf4 = kc >> 2;

        for (int i = tid; i < kc * 32; i += 256) {
            int kk = i >> 5, c4 = i & 31;
            *((float4*)&Ws[kk][0] + c4) =
                *((const float4*)(W + (size_t)(k0 + kk) * 128) + c4);
        }
        for (int i = tid; i < nf4 * 128; i += 256) {
            int row = i / nf4, f4 = i - row * nf4;
            float4 v = *(const float4*)(A + (size_t)(row0 + row) * K + k0 + f4 * 4);
            As[f4 * 4 + 0][row] = v.x;
            As[f4 * 4 + 1][row] = v.y;
            As[f4 * 4 + 2][row] = v.z;
            As[f4 * 4 + 3][row] = v.w;
        }
        __syncthreads();

#pragma unroll 4
        for (int kk = 0; kk < kc; ++kk) {
            float4 b0 = *(const float4*)&Ws[kk][c0];
            float4 b1 = *(const float4*)&Ws[kk][c0 + 4];
            float4 a0 = *(const float4*)&As[kk][r0];
            float4 a1 = *(const float4*)&As[kk][r0 + 4];
            float a[8] = {a0.x, a0.y, a0.z, a0.w, a1.x, a1.y, a1.z, a1.w};
            float b[8] = {b0.x, b0.y, b0.z, b0.w, b1.x, b1.y, b1.z, b1.w};
#pragma unroll
            for (int i = 0; i < 8; ++i)
#pragma unroll
                for (int j = 0; j < 8; ++j)
                    acc[i][j] += a[i] * b[j];
        }
        __syncthreads();
    }

#pragma unroll
    for (int i = 0; i < 8; ++i) {
        int row = row0 + r0 + i;
        float o[8];
#pragma unroll
        for (int j = 0; j < 8; ++j)
            o[j] = fmaxf(acc[i][j] + bias[c0 + j], 0.f);
        float* po = out + (size_t)row * 128 + c0;
        *(float4*)po       = make_float4(o[0], o[1], o[2], o[3]);
        *(float4*)(po + 4) = make_float4(o[4], o[5], o[6], o[7]);
    }
}

// ---------------------------------------------------------------------------
// gemm128<NCUR>: out[row] = dinv_row * (A[row] @ W), K=128, double-buffered
// LDS (reg-staged prefetch, one sync per chunk). dinv from rowptr diffs.
// ---------------------------------------------------------------------------
template<int NCUR>
__global__ __launch_bounds__(256, 2) void gemm128(
    const float* __restrict__ A, const float* __restrict__ W,
    const int* __restrict__ rowptr_g, float* __restrict__ out)
{
    constexpr int KC = 32;
    __shared__ float Ws[2][KC][128];
    __shared__ float As[2][KC][132];
    __shared__ float dinv_ls[128];
    const int tid  = threadIdx.x;
    const int row0 = blockIdx.x * 128;
    const int r0 = (tid >> 4) * 8;
    const int c0 = (tid & 15) * 8;

    if (tid < 128) {
        int row = row0 + tid;
        int gg = row / NCUR, ll = row - gg * NCUR;
        const int* rp = rowptr_g + gg * 513 + ll;
        dinv_ls[tid] = rsqrtf((float)(rp[1] - rp[0] + 1));
    }

    const float4* W4 = (const float4*)W;

#pragma unroll
    for (int j = 0; j < 4; ++j) {
        int i = tid + j * 256;
        int kk = i >> 5, c4 = i & 31;
        *((float4*)&Ws[0][kk][0] + c4) = W4[kk * 32 + c4];
    }
#pragma unroll
    for (int j = 0; j < 4; ++j) {
        int i = tid + j * 256;
        int row = i >> 3, f4 = i & 7;
        float4 v = *(const float4*)(A + (size_t)(row0 + row) * 128 + f4 * 4);
        As[0][f4 * 4 + 0][row] = v.x;
        As[0][f4 * 4 + 1][row] = v.y;
        As[0][f4 * 4 + 2][row] = v.z;
        As[0][f4 * 4 + 3][row] = v.w;
    }
    __syncthreads();

    float acc[8][8];
#pragma unroll
    for (int i = 0; i < 8; ++i)
#pragma unroll
        for (int j = 0; j < 8; ++j) acc[i][j] = 0.f;

    int p = 0;
    for (int k0 = 0; k0 < 128; k0 += KC) {
        const int kn = k0 + KC;
        const bool has = kn < 128;

        float4 wreg[4], areg[4];
        if (has) {
#pragma unroll
            for (int j = 0; j < 4; ++j) {
                int i = tid + j * 256;
                int kk = i >> 5, c4 = i & 31;
                wreg[j] = W4[(kn + kk) * 32 + c4];
            }
#pragma unroll
            for (int j = 0; j < 4; ++j) {
                int i = tid + j * 256;
                int row = i >> 3, f4 = i & 7;
                areg[j] = *(const float4*)(A + (size_t)(row0 + row) * 128 + kn + f4 * 4);
            }
        }

#pragma unroll 4
        for (int kk = 0; kk < KC; ++kk) {
            float4 b0 = *(const float4*)&Ws[p][kk][c0];
            float4 b1 = *(const float4*)&Ws[p][kk][c0 + 4];
            float4 a0 = *(const float4*)&As[p][kk][r0];
            float4 a1 = *(const float4*)&As[p][kk][r0 + 4];
            float a[8] = {a0.x, a0.y, a0.z, a0.w, a1.x, a1.y, a1.z, a1.w};
            float b[8] = {b0.x, b0.y, b0.z, b0.w, b1.x, b1.y, b1.z, b1.w};
#pragma unroll
            for (int i = 0; i < 8; ++i)
#pragma unroll
                for (int j = 0; j < 8; ++j)
                    acc[i][j] += a[i] * b[j];
        }

        if (has) {
            int q = p ^ 1;
#pragma unroll
            for (int j = 0; j < 4; ++j) {
                int i = tid + j * 256;
                int kk = i >> 5, c4 = i & 31;
                *((float4*)&Ws[q][kk][0] + c4) = wreg[j];
            }
#pragma unroll
            for (int j = 0; j < 4; ++j) {
                int i = tid + j * 256;
                int row = i >> 3, f4 = i & 7;
                float4 v = areg[j];
                As[q][f4 * 4 + 0][row] = v.x;
                As[q][f4 * 4 + 1][row] = v.y;
                As[q][f4 * 4 + 2][row] = v.z;
                As[q][f4 * 4 + 3][row] = v.w;
            }
        }
        __syncthreads();
        p ^= 1;
    }

#pragma unroll
    for (int i = 0; i < 8; ++i) {
        int row = row0 + r0 + i;
        float dv = dinv_ls[r0 + i];
        float o[8];
#pragma unroll
        for (int j = 0; j < 8; ++j) o[j] = acc[i][j] * dv;
        float* po = out + (size_t)row * 128 + c0;
        *(float4*)po       = make_float4(o[0], o[1], o[2], o[3]);
        *(float4*)(po + 4) = make_float4(o[4], o[5], o[6], o[7]);
    }
}

// ---------------------------------------------------------------------------
// gather v5: input xs is PRE-SCALED (row r already times dinv_r).
//   grid (G,16), 256 threads, 8 blocks/CU. Dual-row ILP.
// ---------------------------------------------------------------------------
template<int NCUR>
__global__ __launch_bounds__(256, 8) void gather_kernel(
    const float* __restrict__ xs, const unsigned short* __restrict__ csr_g,
    const int* __restrict__ rowptr_g, const float* __restrict__ bvec,
    float* __restrict__ out, float* __restrict__ bnpart)
{
    constexpr int CHUNK = (NCUR + 15) / 16;
    constexpr int CSRCAP = 1536;
    __shared__ int   rowptr_s[CHUNK + 1];
    __shared__ unsigned short csr_s[CSRCAP];
    __shared__ float red_s[512];

    const int g = blockIdx.x, s = blockIdx.y;
    const int tid = threadIdx.x, lane = tid & 63, w = tid >> 6;
    const int nbase = g * NCUR;
    const int d0 = s * CHUNK;
    const int d1 = (d0 + CHUNK < NCUR) ? d0 + CHUNK : NCUR;
    const int len = d1 - d0;

    const int* rp = rowptr_g + g * 513 + d0;
    for (int i = tid; i <= len; i += 256) rowptr_s[i] = rp[i];
    __syncthreads();

    const int base = rowptr_s[0];
    int nume = rowptr_s[len] - base;
    if (nume > CSRCAP) nume = CSRCAP;
    const unsigned short* cg = csr_g + g * EPG + base;
    for (int i = tid; i < nume; i += 256) csr_s[i] = cg[i];
    __syncthreads();

    const float2* x2g = (const float2*)xs + (size_t)nbase * 64 + lane;
    float2* o2p = (float2*)out;
    const float2 b2 = ((const float2*)bvec)[lane];
    float2 sum = make_float2(0.f, 0.f), sq = make_float2(0.f, 0.f);

    for (int da = d0 + w; da < d1; da += 8) {
        const int db = da + 4;
        const bool hb = db < d1;
        const int ra = da - d0, rb = db - d0;
        const int ia = rowptr_s[ra] - base;
        const int na = rowptr_s[ra + 1] - rowptr_s[ra];
        const int ib = hb ? rowptr_s[rb] - base : 0;
        const int nbl = hb ? rowptr_s[rb + 1] - rowptr_s[rb] : 0;
        const float dva = rsqrtf((float)(na + 1));
        const float dvb = rsqrtf((float)(nbl + 1));

        float2 accA = x2g[(size_t)da * 64];
        float2 accB = make_float2(0.f, 0.f);
        if (hb) accB = x2g[(size_t)db * 64];

        const int nmin = na < nbl ? na : nbl;
#pragma unroll 2
        for (int t = 0; t < nmin; ++t) {
            int sa = csr_s[ia + t], sb = csr_s[ib + t];
            float2 va = x2g[(size_t)sa * 64];
            float2 vb = x2g[(size_t)sb * 64];
            accA.x += va.x; accA.y += va.y;
            accB.x += vb.x; accB.y += vb.y;
        }
#pragma unroll 4
        for (int t = nmin; t < na; ++t) {
            float2 va = x2g[(size_t)csr_s[ia + t] * 64];
            accA.x += va.x; accA.y += va.y;
        }
#pragma unroll 4
        for (int t = nmin; t < nbl; ++t) {
            float2 vb = x2g[(size_t)csr_s[ib + t] * 64];
            accB.x += vb.x; accB.y += vb.y;
        }

        float2 oA = make_float2(b2.x + dva * accA.x, b2.y + dva * accA.y);
        o2p[(size_t)(nbase + da) * 64 + lane] = oA;
        sum.x += oA.x; sum.y += oA.y;
        sq.x  += oA.x * oA.x; sq.y += oA.y * oA.y;
        if (hb) {
            float2 oB = make_float2(b2.x + dvb * accB.x, b2.y + dvb * accB.y);
            o2p[(size_t)(nbase + db) * 64 + lane] = oB;
            sum.x += oB.x; sum.y += oB.y;
            sq.x  += oB.x * oB.x; sq.y += oB.y * oB.y;
        }
    }

    float2* red2 = (float2*)red_s;
    red2[tid] = sum; __syncthreads();
    if (tid < 64) {
        float2 a = red2[tid], b_ = red2[tid + 64],
               c = red2[tid + 128], d_ = red2[tid + 192];
        atomicAdd(&bnpart[g * 256 + 2 * tid],     a.x + b_.x + c.x + d_.x);
        atomicAdd(&bnpart[g * 256 + 2 * tid + 1], a.y + b_.y + c.y + d_.y);
    }
    __syncthreads();
    red2[tid] = sq; __syncthreads();
    if (tid < 64) {
        float2 a = red2[tid], b_ = red2[tid + 64],
               c = red2[tid + 128], d_ = red2[tid + 192];
        atomicAdd(&bnpart[g * 256 + 128 + 2 * tid],     a.x + b_.x + c.x + d_.x);
        atomicAdd(&bnpart[g * 256 + 128 + 2 * tid + 1], a.y + b_.y + c.y + d_.y);
    }
}

// ---------------------------------------------------------------------------
// BN finalize + att norm -> coefs[384]. 1024 threads, 8 graph-slices.
// ---------------------------------------------------------------------------
__global__ __launch_bounds__(1024, 1) void bnfin_kernel(
    const float* __restrict__ bnpart, float n,
    const float* __restrict__ gamma, const float* __restrict__ beta,
    const float* __restrict__ att, float* __restrict__ coefs)
{
    __shared__ float ssum[8][128];
    __shared__ float ssq[8][128];
    __shared__ float r[128];
    const int t = threadIdx.x & 127, slice = threadIdx.x >> 7;
    float s = 0.f, q = 0.f;
    for (int g = slice; g < G; g += 8) {
        s += bnpart[g * 256 + t];
        q += bnpart[g * 256 + 128 + t];
    }
    ssum[slice][t] = s; ssq[slice][t] = q;
    if (threadIdx.x < 128) { float av = att[t]; r[t] = av * av; }
    __syncthreads();
    if (threadIdx.x < 128) {
        float S = 0.f, Q = 0.f;
#pragma unroll
        for (int k = 0; k < 8; ++k) { S += ssum[k][t]; Q += ssq[k][t]; }
        for (int st = 64; st > 0; st >>= 1) {
            if (t < st) r[t] += r[t + st];
            __syncthreads();
        }
        float norm = sqrtf(r[0]);
        float mu   = S / n;
        float var  = Q / n - mu * mu;
        float inv  = rsqrtf(var + 1e-5f);
        float a    = gamma[t] * inv;
        coefs[t]        = a;
        coefs[128 + t]  = beta[t] - mu * a;
        coefs[256 + t]  = att[t] / norm;
    }
}

// ---------------------------------------------------------------------------
// pool: 1024 threads per graph. scores -> rank-select -> gate/readout ->
// cmap remap; if BUILD: next layer's CSR+rowptr. coefs precomputed by bnfin.
// ---------------------------------------------------------------------------
template<int NCUR, int KK, bool BUILD>
__global__ __launch_bounds__(1024, 1) void pool_kernel(
    const float* __restrict__ gcn, const float* __restrict__ coefs,
    float* __restrict__ newx, short* __restrict__ cmap,
    float* __restrict__ sread,
    const int* __restrict__ src, const int* __restrict__ dst,
    unsigned short* __restrict__ csr_g, int* __restrict__ rowptr_g)
{
    __shared__ float score_s[NCUR];
    __shared__ unsigned long long key_s[NCUR];
    __shared__ short o2n_s[NCUR];
    __shared__ unsigned short n2o_s[KK];
    __shared__ short cmap_s[NPER];
    __shared__ float2 red2[1024];
    __shared__ int   cnt_s[512];
    __shared__ int   rowptr_s[513];
    __shared__ int   wo_s[512];
    __shared__ int   chunksum_s[9];

    const int g = blockIdx.x, tid = threadIdx.x, lane = tid & 63, w = tid >> 6;
    const int nb = g * NCUR;
    const int ebase = g * EPG, obase = g * NPER;
    const float a0 = coefs[lane],       a1 = coefs[64 + lane];
    const float c0 = coefs[128 + lane], c1 = coefs[192 + lane];
    const float t0 = coefs[256 + lane], t1 = coefs[320 + lane];

    for (int i = tid; i < NPER; i += 1024) cmap_s[i] = cmap[obase + i];

    // A: scores, one wave per node
    for (int i = w; i < NCUR; i += 16) {
        const float* row = gcn + (size_t)(nb + i) * 128;
        float h0 = fmaxf(a0 * row[lane] + c0, 0.f);
        float h1 = fmaxf(a1 * row[64 + lane] + c1, 0.f);
        float p  = h0 * t0 + h1 * t1;
#pragma unroll
        for (int off = 32; off > 0; off >>= 1) p += __shfl_down(p, off);
        if (lane == 0) score_s[i] = tanhf(p);
    }
    __syncthreads();

    // B: composite keys
    for (int i = tid; i < NCUR; i += 1024) {
        unsigned u   = __float_as_uint(score_s[i]);
        unsigned key = (u & 0x80000000u) ? ~u : (u | 0x80000000u);
        key_s[i] = ((unsigned long long)key << 32) |
                   (unsigned long long)(0xFFFFFFFFu - (unsigned)i);
    }
    __syncthreads();

    // C: rank selection
    for (int i = tid; i < NCUR; i += 1024) {
        const unsigned long long ki = key_s[i];
        int r = 0;
#pragma unroll 8
        for (int j = 0; j < NCUR; ++j) r += (key_s[j] > ki) ? 1 : 0;
        o2n_s[i] = (r < KK) ? (short)r : (short)-1;
        if (r < KK) n2o_s[r] = (unsigned short)i;
    }
    __syncthreads();

    // D: gating + newx + readout partials
    float mx0 = -1e30f, mx1 = -1e30f, sm0 = 0.f, sm1 = 0.f;
    for (int j2 = w; j2 < KK; j2 += 16) {
        int old = n2o_s[j2];
        float s = score_s[old];
        const float* row = gcn + (size_t)(nb + old) * 128;
        float h0 = fmaxf(a0 * row[lane] + c0, 0.f) * s;
        float h1 = fmaxf(a1 * row[64 + lane] + c1, 0.f) * s;
        float* orow = newx + (size_t)(g * KK + j2) * 128;
        orow[lane]      = h0;
        orow[64 + lane] = h1;
        mx0 = fmaxf(mx0, h0); mx1 = fmaxf(mx1, h1);
        sm0 += h0; sm1 += h1;
    }
    red2[tid] = make_float2(mx0, mx1);
    __syncthreads();
    if (tid < 64) {
        float m = -1e30f;
#pragma unroll
        for (int w2 = 0; w2 < 16; ++w2) m = fmaxf(m, red2[w2 * 64 + tid].x);
        sread[g * 256 + tid] += m;
    } else if (tid < 128) {
        int l = tid - 64;
        float m = -1e30f;
#pragma unroll
        for (int w2 = 0; w2 < 16; ++w2) m = fmaxf(m, red2[w2 * 64 + l].y);
        sread[g * 256 + tid] += m;
    }
    __syncthreads();
    red2[tid] = make_float2(sm0, sm1);
    __syncthreads();
    if (tid < 64) {
        float sm = 0.f;
#pragma unroll
        for (int w2 = 0; w2 < 16; ++w2) sm += red2[w2 * 64 + tid].x;
        sread[g * 256 + 128 + tid] += sm * (1.0f / KK);
    } else if (tid < 128) {
        int l = tid - 64;
        float sm = 0.f;
#pragma unroll
        for (int w2 = 0; w2 < 16; ++w2) sm += red2[w2 * 64 + l].y;
        sread[g * 256 + 128 + tid] += sm * (1.0f / KK);
    }

    // E: cmap remap
    for (int o = tid; o < NPER; o += 1024) {
        int m = cmap_s[o];
        short nm = (m >= 0) ? o2n_s[m] : (short)-1;
        cmap_s[o] = nm;
        cmap[obase + o] = nm;
    }

    if (!BUILD) return;
    __syncthreads();

    // F: build next layer's CSR
    if (tid < 512) cnt_s[tid] = 0;
    __syncthreads();
    for (int e = tid; e < EPG; e += 1024) {
        int sl = cmap_s[src[ebase + e] - obase];
        int dl = cmap_s[dst[ebase + e] - obase];
        if ((sl | dl) >= 0) atomicAdd(&cnt_s[dl], 1);
    }
    __syncthreads();
    int v = 0, x = 0;
    if (tid < 512) {
        v = cnt_s[tid]; x = v;
#pragma unroll
        for (int d = 1; d < 64; d <<= 1) {
            int y = __shfl_up(x, d);
            if (lane >= d) x += y;
        }
        if (lane == 63) chunksum_s[w] = x;
    }
    __syncthreads();
    if (tid == 0) {
        int acc = 0;
#pragma unroll
        for (int k = 0; k < 8; ++k) { int t = chunksum_s[k]; chunksum_s[k] = acc; acc += t; }
    }
    __syncthreads();
    if (tid < 512) {
        int excl = x - v + chunksum_s[w];
        rowptr_s[tid] = excl; wo_s[tid] = excl;
        if (tid == 511) rowptr_s[512] = excl + v;
    }
    __syncthreads();
    for (int i = tid; i <= 512; i += 1024) rowptr_g[g * 513 + i] = rowptr_s[i];
    for (int e = tid; e < EPG; e += 1024) {
        int sl = cmap_s[src[ebase + e] - obase];
        int dl = cmap_s[dst[ebase + e] - obase];
        if ((sl | dl) >= 0) {
            int pos = atomicAdd(&wo_s[dl], 1);
            csr_g[g * EPG + pos] = (unsigned short)sl;
        }
    }
}

// ---------------------------------------------------------------------------
// final MLP
// ---------------------------------------------------------------------------
__global__ void final_kernel(const float* __restrict__ sread,
                             const float* __restrict__ Wl1,
                             const float* __restrict__ bl1,
                             const float* __restrict__ Wl2,
                             const float* __restrict__ bl2,
                             float* __restrict__ out)
{
    __shared__ float s_s[256];
    __shared__ float hid_s[128];
    int g = blockIdx.x, t = threadIdx.x;
    s_s[t]       = sread[g * 256 + t];
    s_s[128 + t] = sread[g * 256 + 128 + t];
    __syncthreads();
    float acc = bl1[t];
    for (int i = 0; i < 256; ++i) acc += s_s[i] * Wl1[i * 128 + t];
    hid_s[t] = fmaxf(acc, 0.f);
    __syncthreads();
    if (t < 2) {
        float o = bl2[t];
        for (int j = 0; j < 128; ++j) o += hid_s[j] * Wl2[j * 2 + t];
        out[g * 2 + t] = o;
    }
}

// ---------------------------------------------------------------------------
extern "C" void kernel_launch(void* const* d_in, const int* in_sizes, int n_in,
                              void* d_out, int out_size, void* d_ws, size_t ws_size,
                              hipStream_t stream)
{
    const float* x    = (const float*)d_in[0];
    const int*   ei   = (const int*)d_in[1];
    const float* Wp   = (const float*)d_in[3];
    const float* bp   = (const float*)d_in[4];
    const float* W1   = (const float*)d_in[5];
    const float* b1   = (const float*)d_in[6];
    const float* g1   = (const float*)d_in[7];
    const float* be1  = (const float*)d_in[8];
    const float* att1 = (const float*)d_in[9];
    const float* W2   = (const float*)d_in[10];
    const float* b2   = (const float*)d_in[11];
    const float* g2   = (const float*)d_in[12];
    const float* be2  = (const float*)d_in[13];
    const float* att2 = (const float*)d_in[14];
    const float* W3   = (const float*)d_in[15];
    const float* b3   = (const float*)d_in[16];
    const float* g3   = (const float*)d_in[17];
    const float* be3  = (const float*)d_in[18];
    const float* att3 = (const float*)d_in[19];
    const float* Wl1  = (const float*)d_in[20];
    const float* bl1  = (const float*)d_in[21];
    const float* Wl2  = (const float*)d_in[22];
    const float* bl2  = (const float*)d_in[23];
    float* out = (float*)d_out;

    const int* srcp = ei;
    const int* dstp = ei + E_TOT;

    char* ws = (char*)d_ws;
    float*          bufA   = (float*)ws;                      // 33,554,432 B
    float*          bufB   = (float*)(ws + 33554432);         // 33,554,432 B
    unsigned short* csr    = (unsigned short*)(ws + 67108864);//  2,097,152 B
    int*            rowptr = (int*)  (ws + 69206016);         //    262,656 B
    float*          bnpart = (float*)(ws + 69468672);         //    393,216 B (3 layers)
    short*          cmap   = (short*)(ws + 69861888);         //    131,072 B
    float*          sread  = (float*)(ws + 69992960);         //    131,072 B
    float*          coefs  = (float*)(ws + 70124032);         //      1,536 B

    float* bn0 = bnpart;
    float* bn1 = bnpart + G * 256;
    float* bn2 = bnpart + 2 * G * 256;

    init_kernel<<<384, 256, 0, stream>>>(cmap, sread, bnpart);
    csr_build0<<<G, 512, 0, stream>>>(srcp, dstp, csr, rowptr);

    // h0 = relu(x @ Wp + bp)
    gemm_pre<<<512, 256, 0, stream>>>(x, Wp, bp, bufA, NTOT);

    // ---- layer 1 ----
    gemm128<NPER><<<512, 256, 0, stream>>>(bufA, W1, rowptr, bufB);
    gather_kernel<NPER><<<dim3(G, 16), 256, 0, stream>>>(bufB, csr, rowptr, b1, bufA, bn0);
    bnfin_kernel<<<1, 1024, 0, stream>>>(bn0, (float)NTOT, g1, be1, att1, coefs);
    pool_kernel<NPER, KP1, true><<<G, 1024, 0, stream>>>(
        bufA, coefs, bufB, cmap, sread, srcp, dstp, csr, rowptr);

    // ---- layer 2 ----
    gemm128<KP1><<<410, 256, 0, stream>>>(bufB, W2, rowptr, bufA);
    gather_kernel<KP1><<<dim3(G, 16), 256, 0, stream>>>(bufA, csr, rowptr, b2, bufB, bn1);
    bnfin_kernel<<<1, 1024, 0, stream>>>(bn1, (float)(G * KP1), g2, be2, att2, coefs);
    pool_kernel<KP1, KP2, true><<<G, 1024, 0, stream>>>(
        bufB, coefs, bufA, cmap, sread, srcp, dstp, csr, rowptr);

    // ---- layer 3 ----
    gemm128<KP2><<<328, 256, 0, stream>>>(bufA, W3, rowptr, bufB);
    gather_kernel<KP2><<<dim3(G, 16), 256, 0, stream>>>(bufB, csr, rowptr, b3, bufA, bn2);
    bnfin_kernel<<<1, 1024, 0, stream>>>(bn2, (float)(G * KP2), g3, be3, att3, coefs);
    pool_kernel<KP2, KP3, false><<<G, 1024, 0, stream>>>(
        bufA, coefs, bufB, cmap, sread, srcp, dstp, csr, rowptr);

    final_kernel<<<G, 128, 0, stream>>>(sread, Wl1, bl1, Wl2, bl2, out);
}